// Round 11
// baseline (1048.722 us; speedup 1.0000x reference)
//
#include <hip/hip_runtime.h>
#include <math.h>

#define BB 2
#define CDIM 256
#define NHEADS 8
#define HD 32
#define HH 40
#define WW 40
#define NN 1600
#define C3 768
#define SCALE 0.17677669529663687f  // 1/sqrt(32)
#define RTE 8            // rows per block, entropy kernel (2 per wave)

// ---------- helpers ----------
__device__ inline unsigned fkey(float f) {
    unsigned u = __float_as_uint(f);
    return (u & 0x80000000u) ? ~u : (u | 0x80000000u);
}
__device__ inline float finv(unsigned u) {
    unsigned v = (u & 0x80000000u) ? (u ^ 0x80000000u) : ~u;
    return __uint_as_float(v);
}

// reduce-scatter 16 values over 64 lanes; lane l gets total of element bitrev4(l&15)
__device__ inline float reduce_scatter16(float (&v)[16], int lane) {
#pragma unroll
    for (int step = 0; step < 4; step++) {
        const int off = 1 << step;
        const bool up = (lane >> step) & 1;
        const int h = 16 >> (step + 1);
#pragma unroll
        for (int i = 0; i < h; i++) {
            float send = up ? v[i] : v[h + i];
            float recv = __shfl_xor(send, off);
            float keep = up ? v[h + i] : v[i];
            v[i] = keep + recv;
        }
    }
    float r = v[0];
    r += __shfl_xor(r, 16);
    r += __shfl_xor(r, 32);
    return r;
}
__device__ inline int scatter_d16(int lane) {
    int l = lane & 15;
    return ((l & 1) << 3) | ((l & 2) << 1) | ((l & 4) >> 1) | ((l & 8) >> 3);
}

// 64-lane radix select: kth-largest among the wave's 64x25 keys (verified r9/r10)
__device__ inline unsigned radix_select(const unsigned (&kv)[25], int wnt,
                                        unsigned* hist, int lane) {
    unsigned prefixHigh = 0;
    for (int pass = 0; pass < 4; pass++) {
        int shift = 24 - 8 * pass;
#pragma unroll
        for (int i = 0; i < 4; i++) hist[lane * 4 + i] = 0u;
#pragma unroll
        for (int kt = 0; kt < 25; kt++) {
            unsigned u = kv[kt];
            bool ok = (pass == 0) || ((u >> (shift + 8)) == prefixHigh);
            if (ok) atomicAdd(&hist[(u >> shift) & 255u], 1u);
        }
        unsigned sch = 0;
#pragma unroll
        for (int i = 0; i < 4; i++) sch += hist[255 - 4 * lane - i];
        unsigned inc = sch;
#pragma unroll
        for (int dlt = 1; dlt < 64; dlt <<= 1) {
            unsigned tv = __shfl_up(inc, dlt, 64);
            if (lane >= dlt) inc += tv;
        }
        unsigned pref = inc - sch;
        bool found = (pref < (unsigned)wnt) && ((unsigned)wnt <= inc);
        int bsel = -1, wnew = 0;
        if (found) {
            unsigned want2 = (unsigned)wnt - pref, cum = 0;
#pragma unroll
            for (int i = 0; i < 4; i++) {
                int bbin = 255 - 4 * lane - i;
                unsigned c = hist[bbin];
                if (bsel < 0 && cum + c >= want2) { bsel = bbin; wnew = (int)(want2 - cum); }
                cum += c;
            }
        }
        unsigned long long mk = __ballot(found);
        int src = __builtin_ctzll(mk);
        bsel = __shfl(bsel, src);
        wnt = __shfl(wnew, src);
        prefixHigh = (prefixHigh << 8) | (unsigned)bsel;
    }
    return prefixHigh;
}

// ---------- 1x1 conv: 8 output channels per thread ----------
__global__ __launch_bounds__(256) void conv1x1_kernel(const float* __restrict__ x,
                                                      const float* __restrict__ w,
                                                      const float* __restrict__ bias,
                                                      float* __restrict__ out) {
    int blk = blockIdx.x;
    int st = blk % 7;
    int t2 = blk / 7;
    int ocg = t2 % (C3 / 8);
    int b = t2 / (C3 / 8);
    int s = st * 256 + threadIdx.x;
    if (s >= NN) return;
    int oc0 = ocg * 8;
    const float* xb = x + (size_t)b * CDIM * NN + s;
    const float* w0 = w + (size_t)oc0 * CDIM;
    float a[8];
#pragma unroll
    for (int i = 0; i < 8; i++) a[i] = bias[oc0 + i];
#pragma unroll 4
    for (int ic = 0; ic < CDIM; ic++) {
        float xv = xb[(size_t)ic * NN];
#pragma unroll
        for (int i = 0; i < 8; i++) a[i] += w0[i * CDIM + ic] * xv;
    }
    float* ob = out + ((size_t)b * C3 + oc0) * NN + s;
#pragma unroll
    for (int i = 0; i < 8; i++) ob[(size_t)i * NN] = a[i];
}

// ---------- depthwise 3x3 pad1 ----------
__global__ __launch_bounds__(256) void dwconv_kernel(const float* __restrict__ in,
                                                     const float* __restrict__ w,
                                                     const float* __restrict__ bias,
                                                     float* __restrict__ out) {
    int idx = blockIdx.x * 256 + threadIdx.x;
    int s = idx % NN;
    int t = idx / NN;
    int c = t % C3;
    int b = t / C3;
    int y = s / WW, xx = s % WW;
    const float* ib = in + ((size_t)b * C3 + c) * NN;
    const float* wr = w + (size_t)c * 9;
    float acc = bias[c];
#pragma unroll
    for (int ky = 0; ky < 3; ky++) {
        int iy = y + ky - 1;
        if (iy < 0 || iy >= HH) continue;
#pragma unroll
        for (int kx = 0; kx < 3; kx++) {
            int ix = xx + kx - 1;
            if (ix < 0 || ix >= WW) continue;
            acc += wr[ky * 3 + kx] * ib[iy * WW + ix];
        }
    }
    out[idx] = acc;
}

// ---------- phase 1: streaming entropy, float4 j-loads, d-chunked (r9/r10-proven) ----------
__global__ __launch_bounds__(256) void entropy_kernel(const float* __restrict__ qkv,
                                                      float* __restrict__ ent) {
    int blk = blockIdx.x;      // bh*(NN/RTE) + rt
    int rt = blk % (NN / RTE);
    int bh = blk / (NN / RTE);
    int h = bh % NHEADS, b = bh / NHEADS;
    int row0 = rt * RTE;
    __shared__ float Qs[RTE][HD];
    int tid = threadIdx.x;
    const float* qb = qkv + ((size_t)b * C3 + h * HD) * NN;
    const float* kb = qkv + ((size_t)b * C3 + CDIM + h * HD) * NN;
    {
        int r = tid >> 5, d = tid & 31;
        Qs[r][d] = qb[(size_t)d * NN + row0 + r];
    }
    __syncthreads();
    int w = tid >> 6, lane = tid & 63;
    int lr0 = 2 * w, lr1 = lr0 + 1;
    float q0[HD], q1[HD];
#pragma unroll
    for (int d = 0; d < HD; d++) { q0[d] = Qs[lr0][d]; q1[d] = Qs[lr1][d]; }
    float S0 = 0.f, T0 = 0.f, S1 = 0.f, T1 = 0.f;
#pragma unroll 1
    for (int it = 0; it < 6; it++) {
        int j0 = it * 256 + lane * 4;
        float a0[4] = {0.f, 0.f, 0.f, 0.f}, a1[4] = {0.f, 0.f, 0.f, 0.f};
#pragma unroll
        for (int dc = 0; dc < 8; dc++) {
            float4 k0 = *(const float4*)&kb[(size_t)(dc * 4 + 0) * NN + j0];
            float4 k1 = *(const float4*)&kb[(size_t)(dc * 4 + 1) * NN + j0];
            float4 k2 = *(const float4*)&kb[(size_t)(dc * 4 + 2) * NN + j0];
            float4 k3 = *(const float4*)&kb[(size_t)(dc * 4 + 3) * NN + j0];
            float qa0 = q0[dc * 4], qa1 = q0[dc * 4 + 1], qa2 = q0[dc * 4 + 2], qa3 = q0[dc * 4 + 3];
            float qb0 = q1[dc * 4], qb1 = q1[dc * 4 + 1], qb2 = q1[dc * 4 + 2], qb3 = q1[dc * 4 + 3];
            a0[0] += qa0 * k0.x + qa1 * k1.x + qa2 * k2.x + qa3 * k3.x;
            a0[1] += qa0 * k0.y + qa1 * k1.y + qa2 * k2.y + qa3 * k3.y;
            a0[2] += qa0 * k0.z + qa1 * k1.z + qa2 * k2.z + qa3 * k3.z;
            a0[3] += qa0 * k0.w + qa1 * k1.w + qa2 * k2.w + qa3 * k3.w;
            a1[0] += qb0 * k0.x + qb1 * k1.x + qb2 * k2.x + qb3 * k3.x;
            a1[1] += qb0 * k0.y + qb1 * k1.y + qb2 * k2.y + qb3 * k3.y;
            a1[2] += qb0 * k0.z + qb1 * k1.z + qb2 * k2.z + qb3 * k3.z;
            a1[3] += qb0 * k0.w + qb1 * k1.w + qb2 * k2.w + qb3 * k3.w;
        }
#pragma unroll
        for (int jj = 0; jj < 4; jj++) {
            float z0 = a0[jj] * SCALE, z1 = a1[jj] * SCALE;
            float e0 = __expf(z0), e1 = __expf(z1);
            S0 += e0; T0 += e0 * z0;
            S1 += e1; T1 += e1 * z1;
        }
    }
    {   // tail: j = 1536 + lane
        int j = 1536 + lane;
        float a0 = 0.f, a1 = 0.f;
#pragma unroll
        for (int d = 0; d < HD; d++) {
            float kvv = kb[(size_t)d * NN + j];
            a0 += q0[d] * kvv;
            a1 += q1[d] * kvv;
        }
        a0 *= SCALE; a1 *= SCALE;
        float e0 = __expf(a0), e1 = __expf(a1);
        S0 += e0; T0 += e0 * a0;
        S1 += e1; T1 += e1 * a1;
    }
#pragma unroll
    for (int o = 1; o < 64; o <<= 1) {
        S0 += __shfl_xor(S0, o); T0 += __shfl_xor(T0, o);
        S1 += __shfl_xor(S1, o); T1 += __shfl_xor(T1, o);
    }
    if (lane == 0) {
        ent[(size_t)bh * NN + row0 + lr0] = logf(S0) - T0 / S0;
        ent[(size_t)bh * NN + row0 + lr1] = logf(S1) - T1 / S1;
    }
}

// ---------- gate ----------
__global__ void gate_kernel(const float* __restrict__ ent_rows,
                            const float* __restrict__ g1w, const float* __restrict__ g1b,
                            const float* __restrict__ g2w, const float* __restrict__ g2b,
                            int* __restrict__ keep) {
    int bh = blockIdx.x;
    int tid = threadIdx.x;
    __shared__ float red[4];
    float ls = 0.f;
    for (int j = tid; j < NN; j += 256) ls += ent_rows[bh * NN + j];
    for (int o = 32; o > 0; o >>= 1) ls += __shfl_down(ls, o);
    int lane = tid & 63, wid = tid >> 6;
    if (lane == 0) red[wid] = ls;
    __syncthreads();
    if (tid == 0) {
        float ent = (red[0] + red[1] + red[2] + red[3]) / (float)NN;
        float val = g2b[0];
#pragma unroll
        for (int j = 0; j < 16; j++) {
            float hid = ent * g1w[j] + g1b[j];
            if (hid < 0.f) hid = 0.f;
            val += hid * g2w[j];
        }
        float ratio = 0.9f / (1.f + expf(-val)) + 0.1f;
        int kp = (int)ceilf(ratio * (float)NN);
        if (kp < 1) kp = 1;
        if (kp > NN) kp = NN;
        keep[bh] = kp;
    }
}

// ---------- phase 2: 2 rows / 1-wave block; float4 QK into LDS; radix on reg keys;
//            p written back over att; float4 PV with 2x16 d-chunks ----------
__global__ __launch_bounds__(64) void sparse_attn_kernel(const float* __restrict__ qkv,
                                                         const int* __restrict__ keep,
                                                         float* __restrict__ oht) {
    int blk = blockIdx.x;
    int pr = blk % (NN / 2);
    int bh = blk / (NN / 2);
    int h = bh % NHEADS, b = bh / NHEADS;
    int row0 = pr * 2;
    __shared__ float att0[NN];       // 6.4 KB
    __shared__ float att1[NN];       // 6.4 KB
    __shared__ unsigned hist[256];   // 1 KB
    __shared__ float Qs[2][HD];
    int lane = threadIdx.x;          // 0..63, one wave
    const float* qb = qkv + ((size_t)b * C3 + h * HD) * NN;
    const float* kb = qkv + ((size_t)b * C3 + CDIM + h * HD) * NN;
    const float* vb = qkv + ((size_t)b * C3 + 2 * CDIM + h * HD) * NN;
    {
        int r = lane >> 5, d = lane & 31;
        Qs[r][d] = qb[(size_t)d * NN + row0 + r];
    }
    int want = keep[bh];
    __syncthreads();
    float q0[HD], q1[HD];
#pragma unroll
    for (int d = 0; d < HD; d++) { q0[d] = Qs[0][d]; q1[d] = Qs[1][d]; }

    // ---- QK^T (float4 along j, dc-chunked kc) into LDS att rows; raw scores ----
#pragma unroll 1
    for (int it = 0; it < 6; it++) {
        int j0 = it * 256 + lane * 4;
        float a0[4] = {0.f, 0.f, 0.f, 0.f}, a1[4] = {0.f, 0.f, 0.f, 0.f};
#pragma unroll
        for (int dc = 0; dc < 8; dc++) {
            float4 k0 = *(const float4*)&kb[(size_t)(dc * 4 + 0) * NN + j0];
            float4 k1 = *(const float4*)&kb[(size_t)(dc * 4 + 1) * NN + j0];
            float4 k2 = *(const float4*)&kb[(size_t)(dc * 4 + 2) * NN + j0];
            float4 k3 = *(const float4*)&kb[(size_t)(dc * 4 + 3) * NN + j0];
            float qa0 = q0[dc * 4], qa1 = q0[dc * 4 + 1], qa2 = q0[dc * 4 + 2], qa3 = q0[dc * 4 + 3];
            float qb0 = q1[dc * 4], qb1 = q1[dc * 4 + 1], qb2 = q1[dc * 4 + 2], qb3 = q1[dc * 4 + 3];
            a0[0] += qa0 * k0.x + qa1 * k1.x + qa2 * k2.x + qa3 * k3.x;
            a0[1] += qa0 * k0.y + qa1 * k1.y + qa2 * k2.y + qa3 * k3.y;
            a0[2] += qa0 * k0.z + qa1 * k1.z + qa2 * k2.z + qa3 * k3.z;
            a0[3] += qa0 * k0.w + qa1 * k1.w + qa2 * k2.w + qa3 * k3.w;
            a1[0] += qb0 * k0.x + qb1 * k1.x + qb2 * k2.x + qb3 * k3.x;
            a1[1] += qb0 * k0.y + qb1 * k1.y + qb2 * k2.y + qb3 * k3.y;
            a1[2] += qb0 * k0.z + qb1 * k1.z + qb2 * k2.z + qb3 * k3.z;
            a1[3] += qb0 * k0.w + qb1 * k1.w + qb2 * k2.w + qb3 * k3.w;
        }
        float4 s0v, s1v;
        s0v.x = a0[0] * SCALE; s0v.y = a0[1] * SCALE; s0v.z = a0[2] * SCALE; s0v.w = a0[3] * SCALE;
        s1v.x = a1[0] * SCALE; s1v.y = a1[1] * SCALE; s1v.z = a1[2] * SCALE; s1v.w = a1[3] * SCALE;
        *(float4*)&att0[j0] = s0v;
        *(float4*)&att1[j0] = s1v;
    }
    {   // tail: j = 1536 + lane
        int j = 1536 + lane;
        float a0 = 0.f, a1 = 0.f;
#pragma unroll
        for (int d = 0; d < HD; d++) {
            float kvv = kb[(size_t)d * NN + j];
            a0 += q0[d] * kvv;
            a1 += q1[d] * kvv;
        }
        att0[j] = a0 * SCALE;
        att1[j] = a1 * SCALE;
    }
    __syncthreads();   // single wave: cheap; guarantees LDS visibility

    // ---- monotone keys in registers (q regs now dead) ----
    unsigned kv0[25], kv1[25];
#pragma unroll
    for (int it = 0; it < 6; it++) {
        int j0 = it * 256 + lane * 4;
        float4 v0 = *(const float4*)&att0[j0];
        float4 v1 = *(const float4*)&att1[j0];
        kv0[4 * it] = fkey(v0.x); kv0[4 * it + 1] = fkey(v0.y);
        kv0[4 * it + 2] = fkey(v0.z); kv0[4 * it + 3] = fkey(v0.w);
        kv1[4 * it] = fkey(v1.x); kv1[4 * it + 1] = fkey(v1.y);
        kv1[4 * it + 2] = fkey(v1.z); kv1[4 * it + 3] = fkey(v1.w);
    }
    kv0[24] = fkey(att0[1536 + lane]);
    kv1[24] = fkey(att1[1536 + lane]);

    // ---- per-row kth thresholds ----
    unsigned kb0 = radix_select(kv0, want, hist, lane);
    unsigned kb1 = radix_select(kv1, want, hist, lane);

    // ---- keys -> probabilities, written back over att in LDS; accumulate S ----
    float S0 = 0.f, S1 = 0.f;
#pragma unroll
    for (int it = 0; it < 6; it++) {
        int j0 = it * 256 + lane * 4;
        float4 p0v, p1v;
        p0v.x = (kv0[4 * it] >= kb0) ? __expf(finv(kv0[4 * it])) : 0.f;
        p0v.y = (kv0[4 * it + 1] >= kb0) ? __expf(finv(kv0[4 * it + 1])) : 0.f;
        p0v.z = (kv0[4 * it + 2] >= kb0) ? __expf(finv(kv0[4 * it + 2])) : 0.f;
        p0v.w = (kv0[4 * it + 3] >= kb0) ? __expf(finv(kv0[4 * it + 3])) : 0.f;
        p1v.x = (kv1[4 * it] >= kb1) ? __expf(finv(kv1[4 * it])) : 0.f;
        p1v.y = (kv1[4 * it + 1] >= kb1) ? __expf(finv(kv1[4 * it + 1])) : 0.f;
        p1v.z = (kv1[4 * it + 2] >= kb1) ? __expf(finv(kv1[4 * it + 2])) : 0.f;
        p1v.w = (kv1[4 * it + 3] >= kb1) ? __expf(finv(kv1[4 * it + 3])) : 0.f;
        *(float4*)&att0[j0] = p0v;
        *(float4*)&att1[j0] = p1v;
        S0 += p0v.x + p0v.y + p0v.z + p0v.w;
        S1 += p1v.x + p1v.y + p1v.z + p1v.w;
    }
    {   // tail
        int j = 1536 + lane;
        float pt0 = (kv0[24] >= kb0) ? __expf(finv(kv0[24])) : 0.f;
        float pt1 = (kv1[24] >= kb1) ? __expf(finv(kv1[24])) : 0.f;
        att0[j] = pt0; att1[j] = pt1;
        S0 += pt0; S1 += pt1;
    }
#pragma unroll
    for (int o = 1; o < 64; o <<= 1) {
        S0 += __shfl_xor(S0, o);
        S1 += __shfl_xor(S1, o);
    }
    __syncthreads();

    // ---- PV: float4 V loads, 2 d-chunks of 16; p re-read from LDS (kv regs dead) ----
#pragma unroll 1
    for (int dc = 0; dc < 2; dc++) {
        float acc0[16], acc1[16];
#pragma unroll
        for (int i = 0; i < 16; i++) { acc0[i] = 0.f; acc1[i] = 0.f; }
#pragma unroll 1
        for (int it = 0; it < 6; it++) {
            int j0 = it * 256 + lane * 4;
            float4 p0v = *(const float4*)&att0[j0];
            float4 p1v = *(const float4*)&att1[j0];
#pragma unroll
            for (int i = 0; i < 16; i++) {
                float4 v = *(const float4*)&vb[(size_t)(dc * 16 + i) * NN + j0];
                acc0[i] += p0v.x * v.x + p0v.y * v.y + p0v.z * v.z + p0v.w * v.w;
                acc1[i] += p1v.x * v.x + p1v.y * v.y + p1v.z * v.z + p1v.w * v.w;
            }
        }
        {   // tail: j = 1536 + lane
            int j = 1536 + lane;
            float pt0 = att0[j], pt1 = att1[j];
#pragma unroll
            for (int i = 0; i < 16; i++) {
                float vv = vb[(size_t)(dc * 16 + i) * NN + j];
                acc0[i] += pt0 * vv;
                acc1[i] += pt1 * vv;
            }
        }
        float tot0 = reduce_scatter16(acc0, lane);
        float tot1 = reduce_scatter16(acc1, lane);
        int dd = dc * 16 + scatter_d16(lane);
        size_t base = ((size_t)b * CDIM + h * HD + dd) * NN + row0;
        if (lane < 16) oht[base + 0] = tot0 / S0;
        else if (lane < 32) oht[base + 1] = tot1 / S1;
    }
}

// ---------- output projection from oht [b][c][n]: 8 oc per thread ----------
__global__ __launch_bounds__(256) void proj_kernel(const float* __restrict__ oht,
                                                   const float* __restrict__ pw,
                                                   const float* __restrict__ pb,
                                                   float* __restrict__ out) {
    int blk = blockIdx.x;
    int st = blk % 7;
    int t2 = blk / 7;
    int ocg = t2 % (CDIM / 8);
    int b = t2 / (CDIM / 8);
    int s = st * 256 + threadIdx.x;
    if (s >= NN) return;
    int co0 = ocg * 8;
    const float* ib = oht + (size_t)b * CDIM * NN + s;
    const float* w0 = pw + (size_t)co0 * CDIM;
    float a[8];
#pragma unroll
    for (int i = 0; i < 8; i++) a[i] = pb[co0 + i];
#pragma unroll 4
    for (int c = 0; c < CDIM; c++) {
        float xv = ib[(size_t)c * NN];
#pragma unroll
        for (int i = 0; i < 8; i++) a[i] += w0[i * CDIM + c] * xv;
    }
    float* ob = out + ((size_t)b * CDIM + co0) * NN + s;
#pragma unroll
    for (int i = 0; i < 8; i++) ob[(size_t)i * NN] = a[i];
}

extern "C" void kernel_launch(void* const* d_in, const int* in_sizes, int n_in,
                              void* d_out, int out_size, void* d_ws, size_t ws_size,
                              hipStream_t stream) {
    const float* x      = (const float*)d_in[0];
    const float* qkv_w  = (const float*)d_in[1];
    const float* qkv_b  = (const float*)d_in[2];
    const float* pos_w  = (const float*)d_in[3];
    const float* pos_b  = (const float*)d_in[4];
    const float* proj_w = (const float*)d_in[5];
    const float* proj_b = (const float*)d_in[6];
    const float* g1w    = (const float*)d_in[7];
    const float* g1b    = (const float*)d_in[8];
    const float* g2w    = (const float*)d_in[9];
    const float* g2b    = (const float*)d_in[10];
    float* out = (float*)d_out;

    float* ws   = (float*)d_ws;
    float* buf1 = ws;                                  // BB*C3*NN
    float* buf2 = buf1 + (size_t)BB * C3 * NN;         // BB*C3*NN
    float* ent  = buf2 + (size_t)BB * C3 * NN;         // BB*NHEADS*NN
    float* oht  = ent + (size_t)BB * NHEADS * NN;      // BB*CDIM*NN  ([b][c][n])
    int* keep   = (int*)(oht + (size_t)BB * CDIM * NN);

    conv1x1_kernel<<<BB * (C3 / 8) * 7, 256, 0, stream>>>(x, qkv_w, qkv_b, buf1);
    dwconv_kernel<<<BB * C3 * NN / 256, 256, 0, stream>>>(buf1, pos_w, pos_b, buf2);
    entropy_kernel<<<NHEADS * BB * (NN / RTE), 256, 0, stream>>>(buf2, ent);
    gate_kernel<<<BB * NHEADS, 256, 0, stream>>>(ent, g1w, g1b, g2w, g2b, keep);
    sparse_attn_kernel<<<NHEADS * BB * (NN / 2), 64, 0, stream>>>(buf2, keep, oht);
    proj_kernel<<<BB * (CDIM / 8) * 7, 256, 0, stream>>>(oht, proj_w, proj_b, out);
}

// Round 12
// 439.035 us; speedup vs baseline: 2.3887x; 2.3887x over previous
//
#include <hip/hip_runtime.h>
#include <math.h>

#define BB 2
#define CDIM 256
#define NHEADS 8
#define HD 32
#define HH 40
#define WW 40
#define NN 1600
#define C3 768
#define SCALE 0.17677669529663687f  // 1/sqrt(32)
#define RTE 8            // rows per block, entropy kernel (2 per wave)
#define RTS 2            // rows per block, sparse kernel (1 wave)
#define TSTR 2048        // tile stride: 32 d * 64 jl
#define HSTR 51200       // per (b,part,h): 25 tiles * 2048

// ---------- helpers ----------
__device__ inline unsigned fkey(float f) {
    unsigned u = __float_as_uint(f);
    return (u & 0x80000000u) ? ~u : (u | 0x80000000u);
}
__device__ inline float finv(unsigned u) {
    unsigned v = (u & 0x80000000u) ? (u ^ 0x80000000u) : ~u;
    return __uint_as_float(v);
}

// ---------- 1x1 conv: 8 output channels per thread ----------
__global__ __launch_bounds__(256) void conv1x1_kernel(const float* __restrict__ x,
                                                      const float* __restrict__ w,
                                                      const float* __restrict__ bias,
                                                      float* __restrict__ out) {
    int blk = blockIdx.x;
    int st = blk % 7;
    int t2 = blk / 7;
    int ocg = t2 % (C3 / 8);
    int b = t2 / (C3 / 8);
    int s = st * 256 + threadIdx.x;
    if (s >= NN) return;
    int oc0 = ocg * 8;
    const float* xb = x + (size_t)b * CDIM * NN + s;
    const float* w0 = w + (size_t)oc0 * CDIM;
    float a[8];
#pragma unroll
    for (int i = 0; i < 8; i++) a[i] = bias[oc0 + i];
#pragma unroll 4
    for (int ic = 0; ic < CDIM; ic++) {
        float xv = xb[(size_t)ic * NN];
#pragma unroll
        for (int i = 0; i < 8; i++) a[i] += w0[i * CDIM + ic] * xv;
    }
    float* ob = out + ((size_t)b * C3 + oc0) * NN + s;
#pragma unroll
    for (int i = 0; i < 8; i++) ob[(size_t)i * NN] = a[i];
}

// ---------- depthwise 3x3 pad1; writes j-tiled layout [b][part][h][kt][d][jl] ----------
__global__ __launch_bounds__(256) void dwconv_kernel(const float* __restrict__ in,
                                                     const float* __restrict__ w,
                                                     const float* __restrict__ bias,
                                                     float* __restrict__ out_t) {
    int idx = blockIdx.x * 256 + threadIdx.x;
    int s = idx % NN;
    int t = idx / NN;
    int c = t % C3;
    int b = t / C3;
    int y = s / WW, xx = s % WW;
    const float* ib = in + ((size_t)b * C3 + c) * NN;
    const float* wr = w + (size_t)c * 9;
    float acc = bias[c];
#pragma unroll
    for (int ky = 0; ky < 3; ky++) {
        int iy = y + ky - 1;
        if (iy < 0 || iy >= HH) continue;
#pragma unroll
        for (int kx = 0; kx < 3; kx++) {
            int ix = xx + kx - 1;
            if (ix < 0 || ix >= WW) continue;
            acc += wr[ky * 3 + kx] * ib[iy * WW + ix];
        }
    }
    int part = c >> 8;
    int r = c & 255;
    int hh = r >> 5;
    int d = r & 31;
    out_t[((size_t)(b * 3 + part) * NHEADS + hh) * HSTR + (s >> 6) * TSTR + d * 64 + (s & 63)] = acc;
}

// ---------- phase 1: streaming entropy on tiled layout (r8 structure) ----------
__global__ __launch_bounds__(256) void entropy_kernel(const float* __restrict__ qkv_t,
                                                      float* __restrict__ ent) {
    int blk = blockIdx.x;      // bh*(NN/RTE) + rt
    int rt = blk % (NN / RTE);
    int bh = blk / (NN / RTE);
    int h = bh % NHEADS, b = bh / NHEADS;
    int row0 = rt * RTE;
    __shared__ float Qs[RTE][HD];
    int tid = threadIdx.x;
    const float* qt = qkv_t + ((size_t)(b * 3 + 0) * NHEADS + h) * HSTR;
    const float* ktb = qkv_t + ((size_t)(b * 3 + 1) * NHEADS + h) * HSTR;
    {
        int r = tid >> 5, d = tid & 31;
        int row = row0 + r;
        Qs[r][d] = qt[(row >> 6) * TSTR + d * 64 + (row & 63)];
    }
    __syncthreads();
    int w = tid >> 6, lane = tid & 63;
    int lr0 = 2 * w, lr1 = lr0 + 1;
    float q0[HD], q1[HD];
#pragma unroll
    for (int d = 0; d < HD; d++) { q0[d] = Qs[lr0][d]; q1[d] = Qs[lr1][d]; }
    float S0 = 0.f, T0 = 0.f, S1 = 0.f, T1 = 0.f;
#pragma unroll 1
    for (int kt = 0; kt < 25; kt++) {
        const float* kp = ktb + kt * TSTR + lane;
        float a0 = 0.f, a1 = 0.f;
#pragma unroll
        for (int dc = 0; dc < 4; dc++) {
            float kc[8];
#pragma unroll
            for (int i = 0; i < 8; i++) kc[i] = kp[(dc * 8 + i) * 64];
#pragma unroll
            for (int i = 0; i < 8; i++) {
                a0 += q0[dc * 8 + i] * kc[i];
                a1 += q1[dc * 8 + i] * kc[i];
            }
        }
        a0 *= SCALE; a1 *= SCALE;
        float e0 = __expf(a0), e1 = __expf(a1);
        S0 += e0; T0 += e0 * a0;
        S1 += e1; T1 += e1 * a1;
    }
#pragma unroll
    for (int o = 1; o < 64; o <<= 1) {
        S0 += __shfl_xor(S0, o); T0 += __shfl_xor(T0, o);
        S1 += __shfl_xor(S1, o); T1 += __shfl_xor(T1, o);
    }
    if (lane == 0) {
        ent[(size_t)bh * NN + row0 + lr0] = logf(S0) - T0 / S0;
        ent[(size_t)bh * NN + row0 + lr1] = logf(S1) - T1 / S1;
    }
}

// ---------- gate ----------
__global__ void gate_kernel(const float* __restrict__ ent_rows,
                            const float* __restrict__ g1w, const float* __restrict__ g1b,
                            const float* __restrict__ g2w, const float* __restrict__ g2b,
                            int* __restrict__ keep) {
    int bh = blockIdx.x;
    int tid = threadIdx.x;
    __shared__ float red[4];
    float ls = 0.f;
    for (int j = tid; j < NN; j += 256) ls += ent_rows[bh * NN + j];
    for (int o = 32; o > 0; o >>= 1) ls += __shfl_down(ls, o);
    int lane = tid & 63, wid = tid >> 6;
    if (lane == 0) red[wid] = ls;
    __syncthreads();
    if (tid == 0) {
        float ent = (red[0] + red[1] + red[2] + red[3]) / (float)NN;
        float val = g2b[0];
#pragma unroll
        for (int j = 0; j < 16; j++) {
            float hid = ent * g1w[j] + g1b[j];
            if (hid < 0.f) hid = 0.f;
            val += hid * g2w[j];
        }
        float ratio = 0.9f / (1.f + expf(-val)) + 0.1f;
        int kp = (int)ceilf(ratio * (float)NN);
        if (kp < 1) kp = 1;
        if (kp > NN) kp = NN;
        keep[bh] = kp;
    }
}

// ---------- phase 2: r8-exact structure on tiled K/V ----------
__global__ __launch_bounds__(64) void sparse_attn_kernel(const float* __restrict__ qkv_t,
                                                         const int* __restrict__ keep,
                                                         float* __restrict__ oht) {
    int blk = blockIdx.x;
    int rt = blk % (NN / RTS);
    int bh = blk / (NN / RTS);
    int h = bh % NHEADS, b = bh / NHEADS;
    int row0 = rt * RTS;
    __shared__ float att[RTS][NN];       // 12.8 KB
    __shared__ unsigned hist[RTS][256];  // 2 KB
    __shared__ float Qs[RTS][HD];        // 0.25 KB
    int tid = threadIdx.x;               // 0..63, one wave
    const float* qt = qkv_t + ((size_t)(b * 3 + 0) * NHEADS + h) * HSTR;
    const float* ktb = qkv_t + ((size_t)(b * 3 + 1) * NHEADS + h) * HSTR;
    const float* vtb = qkv_t + ((size_t)(b * 3 + 2) * NHEADS + h) * HSTR;
    {
        int r = tid >> 5, d = tid & 31;
        int row = row0 + r;
        Qs[r][d] = qt[(row >> 6) * TSTR + d * 64 + (row & 63)];
    }
    int want = keep[bh];
    __syncthreads();
    int lane = tid;
    float q0[HD], q1[HD];
#pragma unroll
    for (int d = 0; d < HD; d++) { q0[d] = Qs[0][d]; q1[d] = Qs[1][d]; }

    // ---- QK^T into LDS att rows; track per-row max ----
    float m0 = -1e30f, m1 = -1e30f;
    for (int kt = 0; kt < 25; kt++) {
        const float* kp = ktb + kt * TSTR + lane;
        int j = kt * 64 + lane;
        float kc[HD];
#pragma unroll
        for (int d = 0; d < HD; d++) kc[d] = kp[d * 64];
        float a0 = 0.f, a1 = 0.f;
#pragma unroll
        for (int d = 0; d < HD; d++) { a0 += q0[d] * kc[d]; a1 += q1[d] * kc[d]; }
        a0 *= SCALE; a1 *= SCALE;
        att[0][j] = a0;
        att[1][j] = a1;
        m0 = fmaxf(m0, a0); m1 = fmaxf(m1, a1);
    }
#pragma unroll
    for (int off = 1; off < 64; off <<= 1) {
        m0 = fmaxf(m0, __shfl_xor(m0, off));
        m1 = fmaxf(m1, __shfl_xor(m1, off));
    }

    // ---- cache monotone keys in registers (32 lanes per row; rows in half-waves) ----
    int l = lane & 31;
    int r = (lane < 32) ? 0 : 1;
    unsigned kvr[50];
#pragma unroll
    for (int k2 = 0; k2 < 50; k2++) kvr[k2] = fkey(att[r][k2 * 32 + l]);

    // ---- radix select kth-largest from register keys (r8-proven) ----
    unsigned prefixHigh = 0;
    for (int pass = 0; pass < 4; pass++) {
        int shift = 24 - 8 * pass;
#pragma unroll
        for (int i = 0; i < 8; i++) hist[r][248 - 8 * l + i] = 0u;
#pragma unroll
        for (int k2 = 0; k2 < 50; k2++) {
            unsigned u = kvr[k2];
            bool ok = (pass == 0) || ((u >> (shift + 8)) == prefixHigh);
            if (ok) atomicAdd(&hist[r][(u >> shift) & 255u], 1u);
        }
        unsigned sch = 0;
#pragma unroll
        for (int i = 0; i < 8; i++) sch += hist[r][248 - 8 * l + i];
        unsigned inc = sch;
#pragma unroll
        for (int dlt = 1; dlt < 32; dlt <<= 1) {
            unsigned tv = __shfl_up(inc, dlt, 32);
            if (l >= dlt) inc += tv;
        }
        unsigned pref = inc - sch;
        bool found = (pref < (unsigned)want) && ((unsigned)want <= inc);
        int bsel = -1, wnew = 0;
        if (found) {
            unsigned want2 = (unsigned)want - pref, cum = 0;
#pragma unroll
            for (int i = 0; i < 8; i++) {
                int bbin = 255 - 8 * l - i;
                unsigned c = hist[r][bbin];
                if (bsel < 0 && cum + c >= want2) { bsel = bbin; wnew = (int)(want2 - cum); }
                cum += c;
            }
        }
        unsigned long long mk = __ballot(found);
        int src = (lane < 32) ? __builtin_ctzll(mk & 0xffffffffULL)
                              : __builtin_ctzll(mk >> 32) + 32;
        bsel = __shfl(bsel, src);
        want = __shfl(wnew, src);
        prefixHigh = (prefixHigh << 8) | (unsigned)bsel;
    }
    float kth = finv(prefixHigh);
    float kth0 = __shfl(kth, 0);
    float kth1 = __shfl(kth, 32);

    // ---- fused sparse softmax + PV (S accumulated inline) ----
    float acc0[HD], acc1[HD];
#pragma unroll
    for (int d = 0; d < HD; d++) { acc0[d] = 0.f; acc1[d] = 0.f; }
    float S0 = 0.f, S1 = 0.f;
    for (int kt = 0; kt < 25; kt++) {
        const float* vp = vtb + kt * TSTR + lane;
        int j = kt * 64 + lane;
        float a0 = att[0][j];
        float a1 = att[1][j];
        float p0 = (a0 >= kth0) ? __expf(a0 - m0) : 0.f;
        float p1 = (a1 >= kth1) ? __expf(a1 - m1) : 0.f;
        S0 += p0; S1 += p1;
#pragma unroll
        for (int d = 0; d < HD; d++) {
            float vv = vp[d * 64];
            acc0[d] += p0 * vv;
            acc1[d] += p1 * vv;
        }
    }
#pragma unroll
    for (int off = 1; off < 64; off <<= 1) {
        S0 += __shfl_xor(S0, off);
        S1 += __shfl_xor(S1, off);
    }

    // ---- reduce acc over the 64 lanes via LDS scratch (reuses att rows) ----
    float* scratch = &att[0][0];  // 3200 floats; need 64*33=2112
    int dd = lane & 31;
    int jb = (lane < 32) ? 0 : 32;
#pragma unroll
    for (int d = 0; d < HD; d++) scratch[lane * 33 + d] = acc0[d];
    float sum0 = 0.f;
#pragma unroll
    for (int jj = 0; jj < 32; jj++) sum0 += scratch[(jb + jj) * 33 + dd];
    sum0 += __shfl_xor(sum0, 32);
#pragma unroll
    for (int d = 0; d < HD; d++) scratch[lane * 33 + d] = acc1[d];
    float sum1 = 0.f;
#pragma unroll
    for (int jj = 0; jj < 32; jj++) sum1 += scratch[(jb + jj) * 33 + dd];
    sum1 += __shfl_xor(sum1, 32);

    if (lane < 32) {
        size_t base = ((size_t)b * CDIM + h * HD + dd) * NN + row0;
        oht[base + 0] = sum0 / S0;
        oht[base + 1] = sum1 / S1;
    }
}

// ---------- output projection from oht [b][c][n]: 8 oc per thread ----------
__global__ __launch_bounds__(256) void proj_kernel(const float* __restrict__ oht,
                                                   const float* __restrict__ pw,
                                                   const float* __restrict__ pb,
                                                   float* __restrict__ out) {
    int blk = blockIdx.x;
    int st = blk % 7;
    int t2 = blk / 7;
    int ocg = t2 % (CDIM / 8);
    int b = t2 / (CDIM / 8);
    int s = st * 256 + threadIdx.x;
    if (s >= NN) return;
    int co0 = ocg * 8;
    const float* ib = oht + (size_t)b * CDIM * NN + s;
    const float* w0 = pw + (size_t)co0 * CDIM;
    float a[8];
#pragma unroll
    for (int i = 0; i < 8; i++) a[i] = pb[co0 + i];
#pragma unroll 4
    for (int c = 0; c < CDIM; c++) {
        float xv = ib[(size_t)c * NN];
#pragma unroll
        for (int i = 0; i < 8; i++) a[i] += w0[i * CDIM + c] * xv;
    }
    float* ob = out + ((size_t)b * CDIM + co0) * NN + s;
#pragma unroll
    for (int i = 0; i < 8; i++) ob[(size_t)i * NN] = a[i];
}

extern "C" void kernel_launch(void* const* d_in, const int* in_sizes, int n_in,
                              void* d_out, int out_size, void* d_ws, size_t ws_size,
                              hipStream_t stream) {
    const float* x      = (const float*)d_in[0];
    const float* qkv_w  = (const float*)d_in[1];
    const float* qkv_b  = (const float*)d_in[2];
    const float* pos_w  = (const float*)d_in[3];
    const float* pos_b  = (const float*)d_in[4];
    const float* proj_w = (const float*)d_in[5];
    const float* proj_b = (const float*)d_in[6];
    const float* g1w    = (const float*)d_in[7];
    const float* g1b    = (const float*)d_in[8];
    const float* g2w    = (const float*)d_in[9];
    const float* g2b    = (const float*)d_in[10];
    float* out = (float*)d_out;

    float* ws   = (float*)d_ws;
    float* buf1 = ws;                                  // BB*C3*NN  ([b][c][s])
    float* buf2 = buf1 + (size_t)BB * C3 * NN;         // BB*C3*NN  (j-tiled)
    float* ent  = buf2 + (size_t)BB * C3 * NN;         // BB*NHEADS*NN
    float* oht  = ent + (size_t)BB * NHEADS * NN;      // BB*CDIM*NN  ([b][c][n])
    int* keep   = (int*)(oht + (size_t)BB * CDIM * NN);

    conv1x1_kernel<<<BB * (C3 / 8) * 7, 256, 0, stream>>>(x, qkv_w, qkv_b, buf1);
    dwconv_kernel<<<BB * C3 * NN / 256, 256, 0, stream>>>(buf1, pos_w, pos_b, buf2);
    entropy_kernel<<<NHEADS * BB * (NN / RTE), 256, 0, stream>>>(buf2, ent);
    gate_kernel<<<BB * NHEADS, 256, 0, stream>>>(ent, g1w, g1b, g2w, g2b, keep);
    sparse_attn_kernel<<<NHEADS * BB * (NN / RTS), 64, 0, stream>>>(buf2, keep, oht);
    proj_kernel<<<BB * (CDIM / 8) * 7, 256, 0, stream>>>(oht, proj_w, proj_b, out);
}